// Round 7
// baseline (243.922 us; speedup 1.0000x reference)
//
#include <hip/hip_runtime.h>
#include <math.h>

#define NB 2
#define NS 4096
#define NE 768
#define NH 12
#define ND 64
#define NW 256
#define GK NE

typedef __attribute__((ext_vector_type(8))) short short8v;
typedef __attribute__((ext_vector_type(4))) float f32x4;

__device__ __forceinline__ unsigned short f2bf(float f) {
    unsigned u = __float_as_uint(f);
    u += 0x7FFFu + ((u >> 16) & 1u);
    return (unsigned short)(u >> 16);
}

#if __has_builtin(__builtin_amdgcn_global_load_lds)
#define HAVE_GLL 1
#else
#define HAVE_GLL 0
#endif

// ---------------------------------------------------------------------------
// Kernel 0: fp32 -> bf16 conversion of hidden_states and the three weights.
// ---------------------------------------------------------------------------
__global__ __launch_bounds__(256)
void convert_bf16(const float* __restrict__ hs, const float* __restrict__ qw,
                  const float* __restrict__ kw, const float* __restrict__ vw,
                  unsigned short* __restrict__ hsb, unsigned short* __restrict__ Wb)
{
    const int NU_HS = (NB * NS * NE) / 4;
    const int NU_W  = (NE * NE) / 4;
    const int total = NU_HS + 3 * NU_W;
    for (int u = blockIdx.x * 256 + threadIdx.x; u < total; u += gridDim.x * 256) {
        const float4* src;
        unsigned short* dst;
        if (u < NU_HS) {
            src = (const float4*)hs + u;
            dst = hsb + (size_t)u * 4;
        } else {
            int v = u - NU_HS;
            int m = v / NU_W;
            int r = v - m * NU_W;
            const float* wp = (m == 0) ? qw : (m == 1) ? kw : vw;
            src = (const float4*)wp + r;
            dst = Wb + (size_t)m * (NE * NE) + (size_t)r * 4;
        }
        float4 f = *src;
        ushort4 o;
        o.x = f2bf(f.x); o.y = f2bf(f.y); o.z = f2bf(f.z); o.w = f2bf(f.w);
        *(ushort4*)dst = o;
    }
}

// ---------------------------------------------------------------------------
// Kernel 1: fused QKV projection, bf16 MFMA 16x16x32, fp32 accum.
// 128x128 tile, BK=64, 4 waves. XCD-bijective swizzle with bn-OUTER order:
// each XCD owns an 8-row hs slice (1.57 MB, L2-resident) and sweeps it once
// per bn; the W tile stays hot across 8 consecutive blocks. Round-6 counters
// showed the old bm-fast order streamed all 12.6 MB of hs through each L2
// (FETCH 93 MB, latency-bound).
// ---------------------------------------------------------------------------
__global__ __launch_bounds__(256, 3)
void qkv_mfma(const unsigned short* __restrict__ hsb, const unsigned short* __restrict__ Wb,
              const float* __restrict__ qb, const float* __restrict__ kb,
              const float* __restrict__ vb,
              unsigned short* __restrict__ Qg, unsigned short* __restrict__ Kg,
              unsigned short* __restrict__ Vt)
{
    __shared__ unsigned short lA[128 * 64];   // hs tile  [m][k], 16 KB
    __shared__ unsigned short lB[128 * 64];   // W  tile  [n][k], 16 KB

    const int t  = threadIdx.x;
    const int w  = t >> 6;
    const int l  = t & 63;

    // XCD-bijective, bn-outer / bm-inner-8 within each XCD
    const int lin = blockIdx.x;          // 0..1151, dispatch order (1-D grid)
    const int xcd = lin & 7;
    const int i   = lin >> 3;            // 0..143 within XCD
    const int bm  = xcd * 8 + (i & 7);   // 0..63
    const int bn  = i >> 3;              // 0..17

    const int mat = bn / 6;              // 0=Q 1=K 2=V
    const int n0  = (bn % 6) * 128;
    const int m0  = bm * 128;

    const unsigned short* Wm = Wb + (size_t)mat * (NE * NE);

    // staging geometry: per issue a wave covers 8 rows x 128B, source
    // pre-swizzled so LDS[r][slot] = global chunk slot^(r&7) (16B units)
    const int srow = l >> 3;
    const int scol = (((l & 7) ^ srow) << 3);

    // fragment-read geometry
    const int lw   = l & 15;
    const int lk16 = (l >> 4) << 4;
    const int swz  = (l & 7) << 4;
    const int r0   = (w >> 1) * 64;
    const int c0   = (w & 1) * 64;

    f32x4 acc[4][4] = {};

    for (int kt = 0; kt < GK / 64; ++kt) {
        const int k0 = kt * 64;
        __syncthreads();
#pragma unroll
        for (int ii = 0; ii < 4; ++ii) {
            const int rowA = m0 + 32 * w + 8 * ii + srow;
            const int rowB = n0 + 32 * w + 8 * ii + srow;
            const unsigned short* ga = hsb + (size_t)rowA * GK + k0 + scol;
            const unsigned short* gb = Wm  + (size_t)rowB * GK + k0 + scol;
#if HAVE_GLL
            __builtin_amdgcn_global_load_lds(
                (const __attribute__((address_space(1))) void*)ga,
                (__attribute__((address_space(3))) void*)&lA[(32 * w + 8 * ii) * 64], 16, 0, 0);
            __builtin_amdgcn_global_load_lds(
                (const __attribute__((address_space(1))) void*)gb,
                (__attribute__((address_space(3))) void*)&lB[(32 * w + 8 * ii) * 64], 16, 0, 0);
#else
            *(short8v*)&lA[(32 * w + 8 * ii) * 64 + l * 8] = *(const short8v*)ga;
            *(short8v*)&lB[(32 * w + 8 * ii) * 64 + l * 8] = *(const short8v*)gb;
#endif
        }
        __syncthreads();

        // role swap: Q/K want rows=n (A from W), V wants rows=m (A from hs)
        const unsigned short* rT = (mat < 2) ? lB : lA;
        const unsigned short* cT = (mat < 2) ? lA : lB;

#pragma unroll
        for (int kk = 0; kk < 2; ++kk) {
            const int pb = (((kk * 64) + lk16) ^ swz) >> 1;   // phys col in shorts
            short8v a[4], b[4];
#pragma unroll
            for (int r = 0; r < 4; ++r)
                a[r] = *(const short8v*)&rT[(r0 + r * 16 + lw) * 64 + pb];
#pragma unroll
            for (int c = 0; c < 4; ++c)
                b[c] = *(const short8v*)&cT[(c0 + c * 16 + lw) * 64 + pb];
#pragma unroll
            for (int r = 0; r < 4; ++r)
#pragma unroll
                for (int c = 0; c < 4; ++c)
                    acc[r][c] = __builtin_amdgcn_mfma_f32_16x16x32_bf16(a[r], b[c], acc[r][c], 0, 0, 0);
        }
    }

    const float* bias = (mat == 0) ? qb : (mat == 1) ? kb : vb;
    const float scale = (mat == 0) ? 0.125f : 1.0f;

    if (mat < 2) {
        unsigned short* Out = (mat == 0) ? Qg : Kg;
#pragma unroll
        for (int r = 0; r < 4; ++r) {
            const int nf0 = n0 + r0 + r * 16 + ((l >> 4) << 2);
            const float4 b4 = *(const float4*)&bias[nf0];
            const int h  = nf0 >> 6;
            const int d0 = nf0 & 63;
#pragma unroll
            for (int c = 0; c < 4; ++c) {
                const int m  = m0 + c0 + c * 16 + lw;
                const int bb = m >> 12;
                const int s  = m & (NS - 1);
                ushort4 o;
                o.x = f2bf((acc[r][c][0] + b4.x) * scale);
                o.y = f2bf((acc[r][c][1] + b4.y) * scale);
                o.z = f2bf((acc[r][c][2] + b4.z) * scale);
                o.w = f2bf((acc[r][c][3] + b4.w) * scale);
                *(ushort4*)&Out[((size_t)(bb * NH + h) * NS + s) * ND + d0] = o;
            }
        }
    } else {
#pragma unroll
        for (int c = 0; c < 4; ++c) {
            const int nf = n0 + c0 + c * 16 + lw;
            const float bs = bias[nf];
            const int h = nf >> 6;
            const int d = nf & 63;
#pragma unroll
            for (int r = 0; r < 4; ++r) {
                const int m  = m0 + r0 + r * 16 + ((l >> 4) << 2);
                const int bb = m >> 12;
                const int s0 = m & (NS - 1);
                ushort4 o;
                o.x = f2bf(acc[r][c][0] + bs);
                o.y = f2bf(acc[r][c][1] + bs);
                o.z = f2bf(acc[r][c][2] + bs);
                o.w = f2bf(acc[r][c][3] + bs);
                *(ushort4*)&Vt[((size_t)(bb * NH + h) * ND + d) * NS + s0] = o;
            }
        }
    }
}

// ---------------------------------------------------------------------------
// Kernel 2: sliding-window attention, bf16 MFMA, no-max softmax.
// NO K/V LDS STAGING: K and V are L2-resident per XCD (round-5 FETCH proved
// it: 18.7 MB ~= compulsory), so B-fragments are read DIRECTLY from global
// (L2 hits). This removes every __syncthreads from the k-loop; LDS holds
// only the per-wave P buffer (9 KB) with no cross-wave hazards.
// ---------------------------------------------------------------------------
__global__ __launch_bounds__(256, 3)
void swattn_mfma(const unsigned short* __restrict__ Qg, const unsigned short* __restrict__ Kg,
                 const unsigned short* __restrict__ Vt, float* __restrict__ out)
{
    __shared__ unsigned short Ps[4][16 * 72];  // per-wave P [row][key], 9 KB

    const int t  = threadIdx.x;
    const int w  = t >> 6;
    const int l  = t & 63;

    const int blk0 = blockIdx.x;
    const int blk  = (blk0 & 7) * 192 + (blk0 >> 3);   // XCD-bijective
    const int qt   = blk & 63;
    const int bh   = blk >> 6;
    const int i0   = qt * 64;

    const unsigned short* Qp = Qg + (size_t)bh * NS * ND;
    const unsigned short* Kp = Kg + (size_t)bh * NS * ND;
    const unsigned short* Vp = Vt + (size_t)bh * ND * NS;

    const int lw = l & 15;
    const int g4 = l >> 4;

    short8v aq[2];
#pragma unroll
    for (int kk = 0; kk < 2; ++kk)
        aq[kk] = *(const short8v*)&Qp[(size_t)(i0 + w * 16 + lw) * ND + kk * 32 + g4 * 8];

    f32x4 cacc[4] = {};
    float l_part[4] = {0.f, 0.f, 0.f, 0.f};   // per-lane partial row sums

    for (int kt = 0; kt < 9; ++kt) {
        const int kj0 = i0 - NW + kt * 64;
        if (kj0 < 0 || kj0 >= NS) continue;   // uniform skip: tile fully OOB

        // ---- scores: B-frags straight from global K (L2-hit) ----
        f32x4 sc[4];
#pragma unroll
        for (int cf = 0; cf < 4; ++cf) {
            f32x4 z = {0.f, 0.f, 0.f, 0.f};
#pragma unroll
            for (int kk = 0; kk < 2; ++kk) {
                short8v b = *(const short8v*)&Kp[(size_t)(kj0 + cf * 16 + lw) * ND + kk * 32 + g4 * 8];
                z = __builtin_amdgcn_mfma_f32_16x16x32_bf16(aq[kk], b, z, 0, 0, 0);
            }
            sc[cf] = z;
        }

        // ---- band mask (edge tiles only) ----
        if (kt == 0) {
#pragma unroll
            for (int cf = 0; cf < 4; ++cf) {
                const int lk = cf * 16 + lw;
#pragma unroll
                for (int j = 0; j < 4; ++j)
                    if (lk < w * 16 + g4 * 4 + j) sc[cf][j] = -1e30f;
            }
        } else if (kt == 8) {
#pragma unroll
            for (int cf = 0; cf < 4; ++cf) {
                const int lk = cf * 16 + lw;
#pragma unroll
                for (int j = 0; j < 4; ++j)
                    if (lk > w * 16 + g4 * 4 + j) sc[cf][j] = -1e30f;
            }
        }

        // ---- no-max softmax numerator ----
        float p[4][4];
#pragma unroll
        for (int cf = 0; cf < 4; ++cf)
#pragma unroll
            for (int j = 0; j < 4; ++j)
                p[cf][j] = __expf(sc[cf][j]);
#pragma unroll
        for (int j = 0; j < 4; ++j)
            l_part[j] += (p[0][j] + p[1][j]) + (p[2][j] + p[3][j]);

        // ---- P -> per-wave LDS (bf16); wave-private, no barrier needed ----
        unsigned short* Pw = Ps[w];
#pragma unroll
        for (int cf = 0; cf < 4; ++cf)
#pragma unroll
            for (int j = 0; j < 4; ++j)
                Pw[(g4 * 4 + j) * 72 + cf * 16 + lw] = f2bf(p[cf][j]);

        // ---- PV: B-frags straight from global V^T (L2-hit) ----
#pragma unroll
        for (int kk = 0; kk < 2; ++kk) {
            short8v pa = *(const short8v*)&Pw[lw * 72 + kk * 32 + g4 * 8];
#pragma unroll
            for (int df = 0; df < 4; ++df) {
                short8v bv = *(const short8v*)&Vp[(size_t)(df * 16 + lw) * NS + kj0 + kk * 32 + g4 * 8];
                cacc[df] = __builtin_amdgcn_mfma_f32_16x16x32_bf16(pa, bv, cacc[df], 0, 0, 0);
            }
        }
    }

    // ---- one-time lane reduction of row sums, normalize, write out ----
    float l_run[4];
#pragma unroll
    for (int j = 0; j < 4; ++j) {
        float sm = l_part[j];
        sm += __shfl_xor(sm, 1);
        sm += __shfl_xor(sm, 2);
        sm += __shfl_xor(sm, 4);
        sm += __shfl_xor(sm, 8);
        l_run[j] = sm;
    }

    const int bb = bh / NH;
    const int h  = bh - bb * NH;
#pragma unroll
    for (int j = 0; j < 4; ++j) {
        const float inv = 1.f / l_run[j];
        const int s = i0 + w * 16 + g4 * 4 + j;
        float* op = out + ((size_t)bb * NS + s) * NE + h * ND + lw;
#pragma unroll
        for (int df = 0; df < 4; ++df)
            op[df * 16] = cacc[df][j] * inv;
    }
}

// ---------------------------------------------------------------------------
// Launcher. ws layout (bf16 shorts): hsb | Wb[3] | Q | K | V^T  = 53.9 MB.
// ---------------------------------------------------------------------------
extern "C" void kernel_launch(void* const* d_in, const int* in_sizes, int n_in,
                              void* d_out, int out_size, void* d_ws, size_t ws_size,
                              hipStream_t stream) {
    const float* hs = (const float*)d_in[0];
    const float* qw = (const float*)d_in[1];
    const float* qb = (const float*)d_in[2];
    const float* kw = (const float*)d_in[3];
    const float* kb = (const float*)d_in[4];
    const float* vw = (const float*)d_in[5];
    const float* vb = (const float*)d_in[6];
    float* out = (float*)d_out;

    unsigned short* hsb = (unsigned short*)d_ws;
    unsigned short* Wb  = hsb + (size_t)NB * NS * NE;
    unsigned short* Qg  = Wb + 3 * NE * NE;
    unsigned short* Kg  = Qg + (size_t)NB * NH * NS * ND;
    unsigned short* Vg  = Kg + (size_t)NB * NH * NS * ND;

    convert_bf16<<<1968, 256, 0, stream>>>(hs, qw, kw, vw, hsb, Wb);
    qkv_mfma<<<1152, 256, 0, stream>>>(hsb, Wb, qb, kb, vb, Qg, Kg, Vg);
    swattn_mfma<<<NB * NH * (NS / 64), 256, 0, stream>>>(Qg, Kg, Vg, out);
}

// Round 8
// 165.483 us; speedup vs baseline: 1.4740x; 1.4740x over previous
//
#include <hip/hip_runtime.h>
#include <math.h>

#define NB 2
#define NS 4096
#define NE 768
#define NH 12
#define ND 64
#define NW 256
#define GK NE

typedef __attribute__((ext_vector_type(8))) short short8v;
typedef __attribute__((ext_vector_type(4))) float f32x4;

__device__ __forceinline__ unsigned short f2bf(float f) {
    unsigned u = __float_as_uint(f);
    u += 0x7FFFu + ((u >> 16) & 1u);
    return (unsigned short)(u >> 16);
}

#if __has_builtin(__builtin_amdgcn_global_load_lds)
#define HAVE_GLL 1
#else
#define HAVE_GLL 0
#endif

// ---------------------------------------------------------------------------
// Kernel 0: fp32 -> bf16 conversion of hidden_states and the three weights.
// ---------------------------------------------------------------------------
__global__ __launch_bounds__(256)
void convert_bf16(const float* __restrict__ hs, const float* __restrict__ qw,
                  const float* __restrict__ kw, const float* __restrict__ vw,
                  unsigned short* __restrict__ hsb, unsigned short* __restrict__ Wb)
{
    const int NU_HS = (NB * NS * NE) / 4;
    const int NU_W  = (NE * NE) / 4;
    const int total = NU_HS + 3 * NU_W;
    for (int u = blockIdx.x * 256 + threadIdx.x; u < total; u += gridDim.x * 256) {
        const float4* src;
        unsigned short* dst;
        if (u < NU_HS) {
            src = (const float4*)hs + u;
            dst = hsb + (size_t)u * 4;
        } else {
            int v = u - NU_HS;
            int m = v / NU_W;
            int r = v - m * NU_W;
            const float* wp = (m == 0) ? qw : (m == 1) ? kw : vw;
            src = (const float4*)wp + r;
            dst = Wb + (size_t)m * (NE * NE) + (size_t)r * 4;
        }
        float4 f = *src;
        ushort4 o;
        o.x = f2bf(f.x); o.y = f2bf(f.y); o.z = f2bf(f.z); o.w = f2bf(f.w);
        *(ushort4*)dst = o;
    }
}

// ---------------------------------------------------------------------------
// Kernel 1: fused QKV projection, bf16 MFMA 16x16x32, fp32 accum.
// 128x128 tile, BK=64, 4 waves. XCD-bijective swizzle, bn-outer order:
// each XCD owns an 8-row hs slice (1.57 MB, L2-resident) swept once per bn.
// ---------------------------------------------------------------------------
__global__ __launch_bounds__(256, 3)
void qkv_mfma(const unsigned short* __restrict__ hsb, const unsigned short* __restrict__ Wb,
              const float* __restrict__ qb, const float* __restrict__ kb,
              const float* __restrict__ vb,
              unsigned short* __restrict__ Qg, unsigned short* __restrict__ Kg,
              unsigned short* __restrict__ Vt)
{
    __shared__ unsigned short lA[128 * 64];   // hs tile  [m][k], 16 KB
    __shared__ unsigned short lB[128 * 64];   // W  tile  [n][k], 16 KB

    const int t  = threadIdx.x;
    const int w  = t >> 6;
    const int l  = t & 63;

    // XCD-bijective, bn-outer / bm-inner-8 within each XCD
    const int lin = blockIdx.x;          // 0..1151
    const int xcd = lin & 7;
    const int i   = lin >> 3;            // 0..143 within XCD
    const int bm  = xcd * 8 + (i & 7);   // 0..63
    const int bn  = i >> 3;              // 0..17

    const int mat = bn / 6;              // 0=Q 1=K 2=V
    const int n0  = (bn % 6) * 128;
    const int m0  = bm * 128;

    const unsigned short* Wm = Wb + (size_t)mat * (NE * NE);

    const int srow = l >> 3;
    const int scol = (((l & 7) ^ srow) << 3);

    const int lw   = l & 15;
    const int lk16 = (l >> 4) << 4;
    const int swz  = (l & 7) << 4;
    const int r0   = (w >> 1) * 64;
    const int c0   = (w & 1) * 64;

    f32x4 acc[4][4] = {};

    for (int kt = 0; kt < GK / 64; ++kt) {
        const int k0 = kt * 64;
        __syncthreads();
#pragma unroll
        for (int ii = 0; ii < 4; ++ii) {
            const int rowA = m0 + 32 * w + 8 * ii + srow;
            const int rowB = n0 + 32 * w + 8 * ii + srow;
            const unsigned short* ga = hsb + (size_t)rowA * GK + k0 + scol;
            const unsigned short* gb = Wm  + (size_t)rowB * GK + k0 + scol;
#if HAVE_GLL
            __builtin_amdgcn_global_load_lds(
                (const __attribute__((address_space(1))) void*)ga,
                (__attribute__((address_space(3))) void*)&lA[(32 * w + 8 * ii) * 64], 16, 0, 0);
            __builtin_amdgcn_global_load_lds(
                (const __attribute__((address_space(1))) void*)gb,
                (__attribute__((address_space(3))) void*)&lB[(32 * w + 8 * ii) * 64], 16, 0, 0);
#else
            *(short8v*)&lA[(32 * w + 8 * ii) * 64 + l * 8] = *(const short8v*)ga;
            *(short8v*)&lB[(32 * w + 8 * ii) * 64 + l * 8] = *(const short8v*)gb;
#endif
        }
        __syncthreads();

        const unsigned short* rT = (mat < 2) ? lB : lA;
        const unsigned short* cT = (mat < 2) ? lA : lB;

#pragma unroll
        for (int kk = 0; kk < 2; ++kk) {
            const int pb = (((kk * 64) + lk16) ^ swz) >> 1;
            short8v a[4], b[4];
#pragma unroll
            for (int r = 0; r < 4; ++r)
                a[r] = *(const short8v*)&rT[(r0 + r * 16 + lw) * 64 + pb];
#pragma unroll
            for (int c = 0; c < 4; ++c)
                b[c] = *(const short8v*)&cT[(c0 + c * 16 + lw) * 64 + pb];
#pragma unroll
            for (int r = 0; r < 4; ++r)
#pragma unroll
                for (int c = 0; c < 4; ++c)
                    acc[r][c] = __builtin_amdgcn_mfma_f32_16x16x32_bf16(a[r], b[c], acc[r][c], 0, 0, 0);
        }
    }

    const float* bias = (mat == 0) ? qb : (mat == 1) ? kb : vb;
    const float scale = (mat == 0) ? 0.125f : 1.0f;

    if (mat < 2) {
        unsigned short* Out = (mat == 0) ? Qg : Kg;
#pragma unroll
        for (int r = 0; r < 4; ++r) {
            const int nf0 = n0 + r0 + r * 16 + ((l >> 4) << 2);
            const float4 b4 = *(const float4*)&bias[nf0];
            const int h  = nf0 >> 6;
            const int d0 = nf0 & 63;
#pragma unroll
            for (int c = 0; c < 4; ++c) {
                const int m  = m0 + c0 + c * 16 + lw;
                const int bb = m >> 12;
                const int s  = m & (NS - 1);
                ushort4 o;
                o.x = f2bf((acc[r][c][0] + b4.x) * scale);
                o.y = f2bf((acc[r][c][1] + b4.y) * scale);
                o.z = f2bf((acc[r][c][2] + b4.z) * scale);
                o.w = f2bf((acc[r][c][3] + b4.w) * scale);
                *(ushort4*)&Out[((size_t)(bb * NH + h) * NS + s) * ND + d0] = o;
            }
        }
    } else {
#pragma unroll
        for (int c = 0; c < 4; ++c) {
            const int nf = n0 + c0 + c * 16 + lw;
            const float bs = bias[nf];
            const int h = nf >> 6;
            const int d = nf & 63;
#pragma unroll
            for (int r = 0; r < 4; ++r) {
                const int m  = m0 + r0 + r * 16 + ((l >> 4) << 2);
                const int bb = m >> 12;
                const int s0 = m & (NS - 1);
                ushort4 o;
                o.x = f2bf(acc[r][c][0] + bs);
                o.y = f2bf(acc[r][c][1] + bs);
                o.z = f2bf(acc[r][c][2] + bs);
                o.w = f2bf(acc[r][c][3] + bs);
                *(ushort4*)&Vt[((size_t)(bb * NH + h) * ND + d) * NS + s0] = o;
            }
        }
    }
}

// ---------------------------------------------------------------------------
// Kernel 2: sliding-window attention, bf16 MFMA, no-max softmax, LDS-staged
// K/V (round-7 showed direct-global B-frags are latency-poison: 46->126us).
// QBLK=128: each block covers 128 q rows over 10 k-tiles -> staged bytes
// and barriers per MFMA halve vs QBLK=64. 768 blocks = exactly 3/CU.
// Edge masks: lo (kj_local < r) on kt<=1, hi (kj_local > r+512) on kt>=8.
// ---------------------------------------------------------------------------
__global__ __launch_bounds__(256, 3)
void swattn_mfma(const unsigned short* __restrict__ Qg, const unsigned short* __restrict__ Kg,
                 const unsigned short* __restrict__ Vt, float* __restrict__ out)
{
    __shared__ unsigned short Ks[64 * 72];     // [key][d], pitch 72
    __shared__ unsigned short Vs[64 * 72];     // [d][key], pitch 72
    __shared__ unsigned short Ps[4][16 * 72];  // per-wave P [row][key]

    const int t  = threadIdx.x;
    const int w  = t >> 6;
    const int l  = t & 63;

    const int blk0 = blockIdx.x;
    const int blk  = (blk0 & 7) * 96 + (blk0 >> 3);   // XCD-bijective (768=8*96)
    const int qt   = blk & 31;
    const int bh   = blk >> 5;
    const int i0   = qt * 128;

    const unsigned short* Qp = Qg + (size_t)bh * NS * ND;
    const unsigned short* Kp = Kg + (size_t)bh * NS * ND;
    const unsigned short* Vp = Vt + (size_t)bh * ND * NS;

    const int lw = l & 15;
    const int g4 = l >> 4;

    short8v aq[2][2];
#pragma unroll
    for (int rf = 0; rf < 2; ++rf)
#pragma unroll
        for (int kk = 0; kk < 2; ++kk)
            aq[rf][kk] = *(const short8v*)&Qp[(size_t)(i0 + rf * 64 + w * 16 + lw) * ND + kk * 32 + g4 * 8];

    f32x4 cacc[2][4] = {};
    float l_part[2][4] = {};

    for (int kt = 0; kt < 10; ++kt) {
        const int kj0 = i0 - NW + kt * 64;
        if (kj0 < 0 || kj0 >= NS) continue;   // uniform skip: tile fully OOB

        __syncthreads();
#pragma unroll
        for (int r = 0; r < 2; ++r) {
            const int u   = t + 256 * r;
            const int row = u >> 3;
            const int c8  = (u & 7) * 8;
            *(short8v*)&Ks[row * 72 + c8] = *(const short8v*)&Kp[(size_t)(kj0 + row) * ND + c8];
            *(short8v*)&Vs[row * 72 + c8] = *(const short8v*)&Vp[(size_t)row * NS + kj0 + c8];
        }
        __syncthreads();

#pragma unroll
        for (int rf = 0; rf < 2; ++rf) {
            // ---- scores ----
            f32x4 sc[4];
#pragma unroll
            for (int cf = 0; cf < 4; ++cf) {
                f32x4 z = {0.f, 0.f, 0.f, 0.f};
#pragma unroll
                for (int kk = 0; kk < 2; ++kk) {
                    short8v b = *(const short8v*)&Ks[(cf * 16 + lw) * 72 + kk * 32 + g4 * 8];
                    z = __builtin_amdgcn_mfma_f32_16x16x32_bf16(aq[rf][kk], b, z, 0, 0, 0);
                }
                sc[cf] = z;
            }

            // ---- band masks (edge tiles only) ----
            if (kt <= 1) {        // lo edge: invalid iff kj_local < r
#pragma unroll
                for (int cf = 0; cf < 4; ++cf) {
                    const int kjl = kt * 64 + cf * 16 + lw;
#pragma unroll
                    for (int j = 0; j < 4; ++j)
                        if (kjl < rf * 64 + w * 16 + g4 * 4 + j) sc[cf][j] = -1e30f;
                }
            } else if (kt >= 8) { // hi edge: invalid iff kj_local > r + 512
#pragma unroll
                for (int cf = 0; cf < 4; ++cf) {
                    const int kjl = kt * 64 + cf * 16 + lw;
#pragma unroll
                    for (int j = 0; j < 4; ++j)
                        if (kjl > rf * 64 + w * 16 + g4 * 4 + j + 2 * NW) sc[cf][j] = -1e30f;
                }
            }

            // ---- no-max softmax numerator ----
            float p[4][4];
#pragma unroll
            for (int cf = 0; cf < 4; ++cf)
#pragma unroll
                for (int j = 0; j < 4; ++j)
                    p[cf][j] = __expf(sc[cf][j]);
#pragma unroll
            for (int j = 0; j < 4; ++j)
                l_part[rf][j] += (p[0][j] + p[1][j]) + (p[2][j] + p[3][j]);

            // ---- P -> per-wave LDS (bf16); wave-private, no barrier ----
            unsigned short* Pw = Ps[w];
#pragma unroll
            for (int cf = 0; cf < 4; ++cf)
#pragma unroll
                for (int j = 0; j < 4; ++j)
                    Pw[(g4 * 4 + j) * 72 + cf * 16 + lw] = f2bf(p[cf][j]);

            // ---- PV ----
#pragma unroll
            for (int kk = 0; kk < 2; ++kk) {
                short8v pa = *(const short8v*)&Pw[lw * 72 + kk * 32 + g4 * 8];
#pragma unroll
                for (int df = 0; df < 4; ++df) {
                    short8v bv = *(const short8v*)&Vs[(df * 16 + lw) * 72 + kk * 32 + g4 * 8];
                    cacc[rf][df] = __builtin_amdgcn_mfma_f32_16x16x32_bf16(pa, bv, cacc[rf][df], 0, 0, 0);
                }
            }
        }
    }

    // ---- one-time lane reduction of row sums, normalize, write out ----
    const int bb = bh / NH;
    const int h  = bh - bb * NH;
#pragma unroll
    for (int rf = 0; rf < 2; ++rf) {
#pragma unroll
        for (int j = 0; j < 4; ++j) {
            float sm = l_part[rf][j];
            sm += __shfl_xor(sm, 1);
            sm += __shfl_xor(sm, 2);
            sm += __shfl_xor(sm, 4);
            sm += __shfl_xor(sm, 8);
            const float inv = 1.f / sm;
            const int s = i0 + rf * 64 + w * 16 + g4 * 4 + j;
            float* op = out + ((size_t)bb * NS + s) * NE + h * ND + lw;
#pragma unroll
            for (int df = 0; df < 4; ++df)
                op[df * 16] = cacc[rf][df][j] * inv;
        }
    }
}

// ---------------------------------------------------------------------------
// Launcher. ws layout (bf16 shorts): hsb | Wb[3] | Q | K | V^T  = 53.9 MB.
// ---------------------------------------------------------------------------
extern "C" void kernel_launch(void* const* d_in, const int* in_sizes, int n_in,
                              void* d_out, int out_size, void* d_ws, size_t ws_size,
                              hipStream_t stream) {
    const float* hs = (const float*)d_in[0];
    const float* qw = (const float*)d_in[1];
    const float* qb = (const float*)d_in[2];
    const float* kw = (const float*)d_in[3];
    const float* kb = (const float*)d_in[4];
    const float* vw = (const float*)d_in[5];
    const float* vb = (const float*)d_in[6];
    float* out = (float*)d_out;

    unsigned short* hsb = (unsigned short*)d_ws;
    unsigned short* Wb  = hsb + (size_t)NB * NS * NE;
    unsigned short* Qg  = Wb + 3 * NE * NE;
    unsigned short* Kg  = Qg + (size_t)NB * NH * NS * ND;
    unsigned short* Vg  = Kg + (size_t)NB * NH * NS * ND;

    convert_bf16<<<1968, 256, 0, stream>>>(hs, qw, kw, vw, hsb, Wb);
    qkv_mfma<<<1152, 256, 0, stream>>>(hsb, Wb, qb, kb, vb, Qg, Kg, Vg);
    swattn_mfma<<<NB * NH * (NS / 128), 256, 0, stream>>>(Qg, Kg, Vg, out);
}